// Round 1
// baseline (871.737 us; speedup 1.0000x reference)
//
#include <hip/hip_runtime.h>
#include <hip/hip_bf16.h>

// Problem constants (fixed by the reference module)
#define D_MODEL 256
#define NHEAD   8
#define NLVL    4
#define NPTS    4
#define CH      32           // D/NH
#define QTOT    2048
#define BS      8
#define LVTOT   21760        // 128*128 + 64*64 + 32*32 + 16*16
#define KDIM    256

// ---------------------------------------------------------------------------
// Shared fp32 GEMM template: C[row][col] = A[row][:] @ W[:][col] + bias[col]
// K is fixed at 256. Tile: 128 rows x 128 cols per 256-thread block,
// 8x8 micro-tile per thread, K staged in LDS in chunks of 32.
// ---------------------------------------------------------------------------
#define TM 128
#define TN 128
#define KC 32

struct StoreV {
    __hip_bfloat16* v;   // (bs, NH, LV, C)
    __device__ void operator()(int row, int col, float val) const {
        int b = row / LVTOT;
        int i = row - b * LVTOT;
        int h = col >> 5;
        int c = col & 31;
        v[(((size_t)b * NHEAD + h) * LVTOT + i) * CH + c] = __float2bfloat16(val);
    }
};

struct StorePlain {
    float* o;
    int ncol;
    __device__ void operator()(int row, int col, float val) const {
        o[(size_t)row * ncol + col] = val;
    }
};

template <int NCOL, typename Store>
__global__ __launch_bounds__(256)
void gemm_f32(const float* __restrict__ A, const float* __restrict__ W,
              const float* __restrict__ bias, Store store) {
    __shared__ float As[KC][TM];   // 16 KB, k-major
    __shared__ float Bs[KC][TN];   // 16 KB, k-major

    const int tid = threadIdx.x;
    const int tx = tid & 15;       // col group 0..15
    const int ty = tid >> 4;       // row group 0..15
    const int rowBase = blockIdx.x * TM;
    const int colBase = blockIdx.y * TN;

    // staging assignments
    const int ar = tid >> 1;              // A row 0..127
    const int ak = (tid & 1) * 16;        // A k offset 0 or 16
    const int bk = tid >> 3;              // B k 0..31
    const int bc = (tid & 7) * 16;        // B col offset

    float acc[8][8];
#pragma unroll
    for (int i = 0; i < 8; ++i)
#pragma unroll
        for (int j = 0; j < 8; ++j) acc[i][j] = 0.f;

    const float* Arow = A + (size_t)(rowBase + ar) * KDIM;

    for (int kc = 0; kc < KDIM; kc += KC) {
        // stage A (transpose to k-major)
#pragma unroll
        for (int j = 0; j < 4; ++j) {
            float4 t = *(const float4*)(Arow + kc + ak + j * 4);
            As[ak + j * 4 + 0][ar] = t.x;
            As[ak + j * 4 + 1][ar] = t.y;
            As[ak + j * 4 + 2][ar] = t.z;
            As[ak + j * 4 + 3][ar] = t.w;
        }
        // stage B (row-major copy)
#pragma unroll
        for (int j = 0; j < 4; ++j) {
            float4 t = *(const float4*)(W + (size_t)(kc + bk) * NCOL + colBase + bc + j * 4);
            *(float4*)&Bs[bk][bc + j * 4] = t;
        }
        __syncthreads();

#pragma unroll 4
        for (int k = 0; k < KC; ++k) {
            float a[8], b[8];
            *(float4*)&a[0] = *(const float4*)&As[k][ty * 8];
            *(float4*)&a[4] = *(const float4*)&As[k][ty * 8 + 4];
            *(float4*)&b[0] = *(const float4*)&Bs[k][tx * 8];
            *(float4*)&b[4] = *(const float4*)&Bs[k][tx * 8 + 4];
#pragma unroll
            for (int i = 0; i < 8; ++i)
#pragma unroll
                for (int j = 0; j < 8; ++j) acc[i][j] += a[i] * b[j];
        }
        __syncthreads();
    }

#pragma unroll
    for (int i = 0; i < 8; ++i) {
        int row = rowBase + ty * 8 + i;
#pragma unroll
        for (int j = 0; j < 8; ++j) {
            int col = colBase + tx * 8 + j;
            store(row, col, acc[i][j] + bias[col]);
        }
    }
}

// ---------------------------------------------------------------------------
// Fused softmax + deformable sampling.
// 8 queries per 256-thread block. thread = (head = tid>>5, channel = tid&31).
// ---------------------------------------------------------------------------
__global__ __launch_bounds__(256)
void sample_kernel(const float* __restrict__ off_ws,
                   const float* __restrict__ logits_ws,
                   const float* __restrict__ bbox,
                   const __hip_bfloat16* __restrict__ v,
                   float* __restrict__ acc_ws) {
    __shared__ __align__(16) float off_s[8 * 256];
    __shared__ __align__(16) float attn_s[8 * 128];
    __shared__ float bbox_s[8 * 8];

    const int tid = threadIdx.x;
    const long gq0 = (long)blockIdx.x * 8;

    // load off (2048 floats) and logits (1024 floats)
    const float4* osrc = (const float4*)(off_ws + gq0 * 256);
    ((float4*)off_s)[tid] = osrc[tid];
    ((float4*)off_s)[tid + 256] = osrc[tid + 256];
    const float4* lsrc = (const float4*)(logits_ws + gq0 * 128);
    ((float4*)attn_s)[tid] = lsrc[tid];
    if (tid < 64) bbox_s[tid] = bbox[gq0 * 8 + tid];
    __syncthreads();

    // softmax over 16 per (query, head): 64 groups, one thread each
    if (tid < 64) {
        int qq = tid >> 3, h = tid & 7;
        float* p = attn_s + qq * 128 + h * 16;
        float m = p[0];
#pragma unroll
        for (int i = 1; i < 16; ++i) m = fmaxf(m, p[i]);
        float e[16], s = 0.f;
#pragma unroll
        for (int i = 0; i < 16; ++i) { e[i] = __expf(p[i] - m); s += e[i]; }
        float inv = 1.f / s;
#pragma unroll
        for (int i = 0; i < 16; ++i) p[i] = e[i] * inv;
    }
    __syncthreads();

    const int h = tid >> 5, c = tid & 31;
    const int b = (int)(gq0 >> 11);  // Q = 2048
    const __hip_bfloat16* vh = v + ((size_t)b * NHEAD + h) * LVTOT * CH + c;

    const int Wl[4] = {128, 64, 32, 16};
    const int Hl[4] = {128, 64, 32, 16};
    const int St[4] = {0, 16384, 20480, 21504};

    for (int qq = 0; qq < 8; ++qq) {
        float accv = 0.f;
        const float* offq = off_s + qq * 256 + h * 32;
        const float* attq = attn_s + qq * 128 + h * 16;
#pragma unroll
        for (int l = 0; l < 4; ++l) {
            const int Wd = Wl[l], Hd = Hl[l];
            const float bx = bbox_s[qq * 8 + l * 2 + 0];
            const float by = bbox_s[qq * 8 + l * 2 + 1];
            const __hip_bfloat16* base = vh + (size_t)St[l] * CH;
#pragma unroll
            for (int p = 0; p < 4; ++p) {
                float ox = offq[l * 8 + p * 2 + 0];
                float oy = offq[l * 8 + p * 2 + 1];
                float x = bx * (float)Wd + ox - 0.5f;
                float y = by * (float)Hd + oy - 0.5f;
                float x0f = floorf(x), y0f = floorf(y);
                float fx = x - x0f, fy = y - y0f;
                int x0 = (int)x0f, y0 = (int)y0f;
                float att = attq[l * 4 + p];
                float s = 0.f;
                int x1 = x0 + 1, y1 = y0 + 1;
                bool vx0 = (unsigned)x0 < (unsigned)Wd;
                bool vx1 = (unsigned)x1 < (unsigned)Wd;
                bool vy0 = (unsigned)y0 < (unsigned)Hd;
                bool vy1 = (unsigned)y1 < (unsigned)Hd;
                if (vy0) {
                    if (vx0) s += (1.f - fx) * (1.f - fy) * __bfloat162float(base[(size_t)(y0 * Wd + x0) * CH]);
                    if (vx1) s += fx * (1.f - fy) * __bfloat162float(base[(size_t)(y0 * Wd + x1) * CH]);
                }
                if (vy1) {
                    if (vx0) s += (1.f - fx) * fy * __bfloat162float(base[(size_t)(y1 * Wd + x0) * CH]);
                    if (vx1) s += fx * fy * __bfloat162float(base[(size_t)(y1 * Wd + x1) * CH]);
                }
                accv += att * s;
            }
        }
        acc_ws[(gq0 + qq) * 256 + tid] = accv;
    }
}

// ---------------------------------------------------------------------------
extern "C" void kernel_launch(void* const* d_in, const int* in_sizes, int n_in,
                              void* d_out, int out_size, void* d_ws, size_t ws_size,
                              hipStream_t stream) {
    const float* query   = (const float*)d_in[0];   // (8, 2048, 256)
    const float* bbox    = (const float*)d_in[1];   // (8, 2048, 4, 2)
    const float* value   = (const float*)d_in[2];   // (8, 21760, 256)
    // d_in[3] = value_shapes (static, hard-coded)
    const float* W_value = (const float*)d_in[4];
    const float* b_value = (const float*)d_in[5];
    const float* W_off   = (const float*)d_in[6];
    const float* b_off   = (const float*)d_in[7];
    const float* W_attn  = (const float*)d_in[8];
    const float* b_attn  = (const float*)d_in[9];
    const float* W_out   = (const float*)d_in[10];
    const float* b_out   = (const float*)d_in[11];
    float* out = (float*)d_out;

    // workspace layout
    char* ws = (char*)d_ws;
    __hip_bfloat16* v_ws = (__hip_bfloat16*)ws;                    // 89,128,960 B
    float* off_ws    = (float*)(ws + 89128960);                    // 16,777,216 B
    float* logits_ws = (float*)(ws + 89128960 + 16777216);         //  8,388,608 B
    float* acc_ws    = (float*)(ws + 89128960 + 16777216 + 8388608); // 16,777,216 B

    const int NQ = BS * QTOT;          // 16384
    const int NVROWS = BS * LVTOT;     // 174080

    // 1. value projection -> bf16 v_ws in (b, h, pix, c) layout
    gemm_f32<256, StoreV><<<dim3(NVROWS / TM, 2), 256, 0, stream>>>(
        value, W_value, b_value, StoreV{v_ws});

    // 2. offsets: query @ W_off + b_off
    gemm_f32<256, StorePlain><<<dim3(NQ / TM, 2), 256, 0, stream>>>(
        query, W_off, b_off, StorePlain{off_ws, 256});

    // 3. attention logits: query @ W_attn + b_attn
    gemm_f32<128, StorePlain><<<dim3(NQ / TM, 1), 256, 0, stream>>>(
        query, W_attn, b_attn, StorePlain{logits_ws, 128});

    // 4. softmax + deformable sampling -> acc_ws (16384 x 256)
    sample_kernel<<<NQ / 8, 256, 0, stream>>>(off_ws, logits_ws, bbox, v_ws, acc_ws);

    // 5. output projection -> d_out
    gemm_f32<256, StorePlain><<<dim3(NQ / TM, 2), 256, 0, stream>>>(
        acc_ws, W_out, b_out, StorePlain{out, 256});
}

// Round 2
// 624.298 us; speedup vs baseline: 1.3963x; 1.3963x over previous
//
#include <hip/hip_runtime.h>
#include <hip/hip_bf16.h>

// Problem constants (fixed by the reference module)
#define D_MODEL 256
#define NHEAD   8
#define NLVL    4
#define NPTS    4
#define CH      32           // D/NH
#define QTOT    2048
#define BS      8
#define LVTOT   21760        // 128*128 + 64*64 + 32*32 + 16*16
#define KDIM    256

typedef __attribute__((ext_vector_type(8))) short bf16x8;
typedef __attribute__((ext_vector_type(4))) float f32x4;

// ---------------------------------------------------------------------------
// W_value fp32 [k][n] -> Wt bf16 [n][k]  (256x256, tiny)
// ---------------------------------------------------------------------------
__global__ __launch_bounds__(256)
void convert_W(const float* __restrict__ W, __hip_bfloat16* __restrict__ Wt) {
    int t = blockIdx.x * 256 + threadIdx.x;   // 0..65535
    int k = t >> 8, n = t & 255;
    Wt[n * 256 + k] = __float2bfloat16(W[k * 256 + n]);
}

// ---------------------------------------------------------------------------
// Value projection via bf16 MFMA.
// Tile: 128 rows x 256 cols (full N) per 256-thread block; A read once.
// 4 waves, each 64x128: acc[4][8] frags of 16x16x32.
// LDS rows padded to 72 bf16 -> 2-way bank aliasing only (free).
// fp32->bf16 conversion fused into A staging.
// ---------------------------------------------------------------------------
#define BK  64
#define LDP 72   // padded LDS row stride (bf16 elements)

__global__ __launch_bounds__(256, 2)
void gemm_value_mfma(const float* __restrict__ A,
                     const __hip_bfloat16* __restrict__ Wt,
                     const float* __restrict__ bias,
                     __hip_bfloat16* __restrict__ v) {
    __shared__ __align__(16) __hip_bfloat16 As[128 * LDP];  // 18,432 B
    __shared__ __align__(16) __hip_bfloat16 Bs[256 * LDP];  // 36,864 B

    const int tid  = threadIdx.x;
    const int lane = tid & 63;
    const int wave = tid >> 6;
    const int wr   = wave >> 1;      // m offset wr*64
    const int wc   = wave & 1;       // n offset wc*128
    const int rowBase = blockIdx.x * 128;

    const int m0   = lane & 15;
    const int quad = lane >> 4;

    // staging assignment: thread covers row sr, k-halfchunk sk..sk+31
    const int sr = tid >> 1;
    const int sk = (tid & 1) * 32;

    f32x4 acc[4][8] = {};

    for (int kc = 0; kc < KDIM; kc += BK) {
        // ---- stage A: fp32 load, convert, bf16 LDS write ----
        const float* ap = A + (size_t)(rowBase + sr) * KDIM + kc + sk;
#pragma unroll
        for (int j = 0; j < 4; ++j) {
            float4 f0 = *(const float4*)(ap + j * 8);
            float4 f1 = *(const float4*)(ap + j * 8 + 4);
            __align__(16) __hip_bfloat16 t8[8];
            t8[0] = __float2bfloat16(f0.x); t8[1] = __float2bfloat16(f0.y);
            t8[2] = __float2bfloat16(f0.z); t8[3] = __float2bfloat16(f0.w);
            t8[4] = __float2bfloat16(f1.x); t8[5] = __float2bfloat16(f1.y);
            t8[6] = __float2bfloat16(f1.z); t8[7] = __float2bfloat16(f1.w);
            *(uint4*)&As[sr * LDP + sk + j * 8] = *(const uint4*)t8;
        }
        // ---- stage B: straight bf16 copy from pre-transposed Wt [n][k] ----
        const uint4* bp = (const uint4*)(Wt + (size_t)tid * KDIM + kc);
#pragma unroll
        for (int j = 0; j < 8; ++j)
            *(uint4*)&Bs[tid * LDP + j * 8] = bp[j];
        __syncthreads();

        // ---- MFMA: 2 k-steps of 32 ----
#pragma unroll
        for (int ks = 0; ks < 2; ++ks) {
            bf16x8 af[4], bfv[8];
#pragma unroll
            for (int i = 0; i < 4; ++i)
                af[i] = *(const bf16x8*)&As[(wr * 64 + i * 16 + m0) * LDP + ks * 32 + quad * 8];
#pragma unroll
            for (int j = 0; j < 8; ++j)
                bfv[j] = *(const bf16x8*)&Bs[(wc * 128 + j * 16 + m0) * LDP + ks * 32 + quad * 8];
#pragma unroll
            for (int i = 0; i < 4; ++i)
#pragma unroll
                for (int j = 0; j < 8; ++j)
                    acc[i][j] = __builtin_amdgcn_mfma_f32_16x16x32_bf16(af[i], bfv[j], acc[i][j], 0, 0, 0);
        }
        __syncthreads();
    }

    // ---- epilogue: bias + store bf16 to v (b, h, pix, c) layout ----
    // 21760 % 128 != straddle: 21760/128 = 170 exactly, so one batch per block
    const int b = rowBase / LVTOT;
    const int pixBase = rowBase - b * LVTOT + wr * 64;
#pragma unroll
    for (int j = 0; j < 8; ++j) {
        const int gcol = wc * 128 + j * 16 + m0;   // C/D: col = lane&15
        const int h = gcol >> 5, c = gcol & 31;
        const float bv = bias[gcol];
        __hip_bfloat16* vp = v + ((size_t)(b * NHEAD + h) * LVTOT) * CH + c;
#pragma unroll
        for (int i = 0; i < 4; ++i) {
            const int pix0 = pixBase + i * 16 + quad * 4;  // C/D: row = quad*4 + r
#pragma unroll
            for (int r = 0; r < 4; ++r)
                vp[(size_t)(pix0 + r) * CH] = __float2bfloat16(acc[i][j][r] + bv);
        }
    }
}

// ---------------------------------------------------------------------------
// fp32 vector GEMM (off / attn / out projections), unchanged from round 1
// ---------------------------------------------------------------------------
#define TM 128
#define TN 128
#define KC 32

struct StorePlain {
    float* o;
    int ncol;
    __device__ void operator()(int row, int col, float val) const {
        o[(size_t)row * ncol + col] = val;
    }
};

template <int NCOL, typename Store>
__global__ __launch_bounds__(256)
void gemm_f32(const float* __restrict__ A, const float* __restrict__ W,
              const float* __restrict__ bias, Store store) {
    __shared__ float As[KC][TM];
    __shared__ float Bs[KC][TN];

    const int tid = threadIdx.x;
    const int tx = tid & 15;
    const int ty = tid >> 4;
    const int rowBase = blockIdx.x * TM;
    const int colBase = blockIdx.y * TN;

    const int ar = tid >> 1;
    const int ak = (tid & 1) * 16;
    const int bk = tid >> 3;
    const int bc = (tid & 7) * 16;

    float acc[8][8];
#pragma unroll
    for (int i = 0; i < 8; ++i)
#pragma unroll
        for (int j = 0; j < 8; ++j) acc[i][j] = 0.f;

    const float* Arow = A + (size_t)(rowBase + ar) * KDIM;

    for (int kc = 0; kc < KDIM; kc += KC) {
#pragma unroll
        for (int j = 0; j < 4; ++j) {
            float4 t = *(const float4*)(Arow + kc + ak + j * 4);
            As[ak + j * 4 + 0][ar] = t.x;
            As[ak + j * 4 + 1][ar] = t.y;
            As[ak + j * 4 + 2][ar] = t.z;
            As[ak + j * 4 + 3][ar] = t.w;
        }
#pragma unroll
        for (int j = 0; j < 4; ++j) {
            float4 t = *(const float4*)(W + (size_t)(kc + bk) * NCOL + colBase + bc + j * 4);
            *(float4*)&Bs[bk][bc + j * 4] = t;
        }
        __syncthreads();

#pragma unroll 4
        for (int k = 0; k < KC; ++k) {
            float a[8], b[8];
            *(float4*)&a[0] = *(const float4*)&As[k][ty * 8];
            *(float4*)&a[4] = *(const float4*)&As[k][ty * 8 + 4];
            *(float4*)&b[0] = *(const float4*)&Bs[k][tx * 8];
            *(float4*)&b[4] = *(const float4*)&Bs[k][tx * 8 + 4];
#pragma unroll
            for (int i = 0; i < 8; ++i)
#pragma unroll
                for (int j = 0; j < 8; ++j) acc[i][j] += a[i] * b[j];
        }
        __syncthreads();
    }

#pragma unroll
    for (int i = 0; i < 8; ++i) {
        int row = rowBase + ty * 8 + i;
#pragma unroll
        for (int j = 0; j < 8; ++j) {
            int col = colBase + tx * 8 + j;
            store(row, col, acc[i][j] + bias[col]);
        }
    }
}

// ---------------------------------------------------------------------------
// Fused softmax + deformable sampling (unchanged from round 1)
// ---------------------------------------------------------------------------
__global__ __launch_bounds__(256)
void sample_kernel(const float* __restrict__ off_ws,
                   const float* __restrict__ logits_ws,
                   const float* __restrict__ bbox,
                   const __hip_bfloat16* __restrict__ v,
                   float* __restrict__ acc_ws) {
    __shared__ __align__(16) float off_s[8 * 256];
    __shared__ __align__(16) float attn_s[8 * 128];
    __shared__ float bbox_s[8 * 8];

    const int tid = threadIdx.x;
    const long gq0 = (long)blockIdx.x * 8;

    const float4* osrc = (const float4*)(off_ws + gq0 * 256);
    ((float4*)off_s)[tid] = osrc[tid];
    ((float4*)off_s)[tid + 256] = osrc[tid + 256];
    const float4* lsrc = (const float4*)(logits_ws + gq0 * 128);
    ((float4*)attn_s)[tid] = lsrc[tid];
    if (tid < 64) bbox_s[tid] = bbox[gq0 * 8 + tid];
    __syncthreads();

    if (tid < 64) {
        int qq = tid >> 3, h = tid & 7;
        float* p = attn_s + qq * 128 + h * 16;
        float m = p[0];
#pragma unroll
        for (int i = 1; i < 16; ++i) m = fmaxf(m, p[i]);
        float e[16], s = 0.f;
#pragma unroll
        for (int i = 0; i < 16; ++i) { e[i] = __expf(p[i] - m); s += e[i]; }
        float inv = 1.f / s;
#pragma unroll
        for (int i = 0; i < 16; ++i) p[i] = e[i] * inv;
    }
    __syncthreads();

    const int h = tid >> 5, c = tid & 31;
    const int b = (int)(gq0 >> 11);  // Q = 2048
    const __hip_bfloat16* vh = v + ((size_t)b * NHEAD + h) * LVTOT * CH + c;

    const int Wl[4] = {128, 64, 32, 16};
    const int Hl[4] = {128, 64, 32, 16};
    const int St[4] = {0, 16384, 20480, 21504};

    for (int qq = 0; qq < 8; ++qq) {
        float accv = 0.f;
        const float* offq = off_s + qq * 256 + h * 32;
        const float* attq = attn_s + qq * 128 + h * 16;
#pragma unroll
        for (int l = 0; l < 4; ++l) {
            const int Wd = Wl[l], Hd = Hl[l];
            const float bx = bbox_s[qq * 8 + l * 2 + 0];
            const float by = bbox_s[qq * 8 + l * 2 + 1];
            const __hip_bfloat16* base = vh + (size_t)St[l] * CH;
#pragma unroll
            for (int p = 0; p < 4; ++p) {
                float ox = offq[l * 8 + p * 2 + 0];
                float oy = offq[l * 8 + p * 2 + 1];
                float x = bx * (float)Wd + ox - 0.5f;
                float y = by * (float)Hd + oy - 0.5f;
                float x0f = floorf(x), y0f = floorf(y);
                float fx = x - x0f, fy = y - y0f;
                int x0 = (int)x0f, y0 = (int)y0f;
                float att = attq[l * 4 + p];
                float s = 0.f;
                int x1 = x0 + 1, y1 = y0 + 1;
                bool vx0 = (unsigned)x0 < (unsigned)Wd;
                bool vx1 = (unsigned)x1 < (unsigned)Wd;
                bool vy0 = (unsigned)y0 < (unsigned)Hd;
                bool vy1 = (unsigned)y1 < (unsigned)Hd;
                if (vy0) {
                    if (vx0) s += (1.f - fx) * (1.f - fy) * __bfloat162float(base[(size_t)(y0 * Wd + x0) * CH]);
                    if (vx1) s += fx * (1.f - fy) * __bfloat162float(base[(size_t)(y0 * Wd + x1) * CH]);
                }
                if (vy1) {
                    if (vx0) s += (1.f - fx) * fy * __bfloat162float(base[(size_t)(y1 * Wd + x0) * CH]);
                    if (vx1) s += fx * fy * __bfloat162float(base[(size_t)(y1 * Wd + x1) * CH]);
                }
                accv += att * s;
            }
        }
        acc_ws[(gq0 + qq) * 256 + tid] = accv;
    }
}

// ---------------------------------------------------------------------------
extern "C" void kernel_launch(void* const* d_in, const int* in_sizes, int n_in,
                              void* d_out, int out_size, void* d_ws, size_t ws_size,
                              hipStream_t stream) {
    const float* query   = (const float*)d_in[0];
    const float* bbox    = (const float*)d_in[1];
    const float* value   = (const float*)d_in[2];
    const float* W_value = (const float*)d_in[4];
    const float* b_value = (const float*)d_in[5];
    const float* W_off   = (const float*)d_in[6];
    const float* b_off   = (const float*)d_in[7];
    const float* W_attn  = (const float*)d_in[8];
    const float* b_attn  = (const float*)d_in[9];
    const float* W_out   = (const float*)d_in[10];
    const float* b_out   = (const float*)d_in[11];
    float* out = (float*)d_out;

    // workspace layout
    char* ws = (char*)d_ws;
    __hip_bfloat16* v_ws = (__hip_bfloat16*)ws;                      // 89,128,960 B
    float* off_ws    = (float*)(ws + 89128960);                      // 16,777,216 B
    float* logits_ws = (float*)(ws + 89128960 + 16777216);           //  8,388,608 B
    float* acc_ws    = (float*)(ws + 89128960 + 16777216 + 8388608); // 16,777,216 B
    // Wt (bf16 256x256 = 131,072 B) overlays the logits region: it is fully
    // consumed by gemm_value_mfma BEFORE the attn-logits GEMM writes logits
    // (stream-ordered), so no extra workspace is needed.
    __hip_bfloat16* Wt = (__hip_bfloat16*)logits_ws;

    const int NQ = BS * QTOT;          // 16384
    const int NVROWS = BS * LVTOT;     // 174080

    // 0. transpose + convert W_value -> Wt bf16 [n][k]
    convert_W<<<256, 256, 0, stream>>>(W_value, Wt);

    // 1. value projection (bf16 MFMA) -> v_ws (b, h, pix, c)
    gemm_value_mfma<<<NVROWS / 128, 256, 0, stream>>>(value, Wt, b_value, v_ws);

    // 2. offsets: query @ W_off + b_off
    gemm_f32<256, StorePlain><<<dim3(NQ / TM, 2), 256, 0, stream>>>(
        query, W_off, b_off, StorePlain{off_ws, 256});

    // 3. attention logits: query @ W_attn + b_attn (overwrites Wt region, OK)
    gemm_f32<128, StorePlain><<<dim3(NQ / TM, 1), 256, 0, stream>>>(
        query, W_attn, b_attn, StorePlain{logits_ws, 128});

    // 4. softmax + deformable sampling -> acc_ws (16384 x 256)
    sample_kernel<<<NQ / 8, 256, 0, stream>>>(off_ws, logits_ws, bbox, v_ws, acc_ws);

    // 5. output projection -> d_out
    gemm_f32<256, StorePlain><<<dim3(NQ / TM, 2), 256, 0, stream>>>(
        acc_ws, W_out, b_out, StorePlain{out, 256});
}

// Round 3
// 408.749 us; speedup vs baseline: 2.1327x; 1.5273x over previous
//
#include <hip/hip_runtime.h>
#include <hip/hip_bf16.h>

// Problem constants (fixed by the reference module)
#define D_MODEL 256
#define NHEAD   8
#define NLVL    4
#define NPTS    4
#define CH      32           // D/NH
#define QTOT    2048
#define BS      8
#define LVTOT   21760        // 128*128 + 64*64 + 32*32 + 16*16
#define KDIM    256

typedef __attribute__((ext_vector_type(8))) short bf16x8;
typedef __attribute__((ext_vector_type(4))) float f32x4;

__device__ inline float bf_lo(unsigned u) { unsigned t = u << 16; float f; __builtin_memcpy(&f, &t, 4); return f; }
__device__ inline float bf_hi(unsigned u) { unsigned t = u & 0xffff0000u; float f; __builtin_memcpy(&f, &t, 4); return f; }
__device__ inline float bfu2f(unsigned short s) { unsigned t = (unsigned)s << 16; float f; __builtin_memcpy(&f, &t, 4); return f; }
__device__ inline unsigned short f2bfu(float f) { __hip_bfloat16 h = __float2bfloat16(f); unsigned short u; __builtin_memcpy(&u, &h, 2); return u; }

// ---------------------------------------------------------------------------
// Generic weight transpose+convert: W fp32 [256][ncols] -> Wt bf16 [ncols][256]
// ncols is a power of two (128 or 256); pass sh = log2(ncols).
// ---------------------------------------------------------------------------
__global__ __launch_bounds__(256)
void convert_W(const float* __restrict__ W, __hip_bfloat16* __restrict__ Wt, int sh) {
    int t = blockIdx.x * 256 + threadIdx.x;
    int k = t >> sh, n = t & ((1 << sh) - 1);
    Wt[n * 256 + k] = __float2bfloat16(W[(k << sh) + n]);
}

// query fp32 -> bf16 (4 elems/thread)
__global__ __launch_bounds__(256)
void convert_q(const float* __restrict__ q, __hip_bfloat16* __restrict__ qb) {
    int t = blockIdx.x * 256 + threadIdx.x;
    float4 f = ((const float4*)q)[t];
    __hip_bfloat16 h4[4] = {__float2bfloat16(f.x), __float2bfloat16(f.y),
                            __float2bfloat16(f.z), __float2bfloat16(f.w)};
    ((uint2*)qb)[t] = *(const uint2*)h4;
}

// ---------------------------------------------------------------------------
// Value projection via bf16 MFMA (unchanged from round 2 — verified).
// ---------------------------------------------------------------------------
#define BK  64
#define LDP 72   // padded LDS row stride (bf16 elements)

__global__ __launch_bounds__(256, 2)
void gemm_value_mfma(const float* __restrict__ A,
                     const __hip_bfloat16* __restrict__ Wt,
                     const float* __restrict__ bias,
                     __hip_bfloat16* __restrict__ v) {
    __shared__ __align__(16) __hip_bfloat16 As[128 * LDP];
    __shared__ __align__(16) __hip_bfloat16 Bs[256 * LDP];

    const int tid  = threadIdx.x;
    const int lane = tid & 63;
    const int wave = tid >> 6;
    const int wr   = wave >> 1;
    const int wc   = wave & 1;
    const int rowBase = blockIdx.x * 128;

    const int m0   = lane & 15;
    const int quad = lane >> 4;

    const int sr = tid >> 1;
    const int sk = (tid & 1) * 32;

    f32x4 acc[4][8] = {};

    for (int kc = 0; kc < KDIM; kc += BK) {
        const float* ap = A + (size_t)(rowBase + sr) * KDIM + kc + sk;
#pragma unroll
        for (int j = 0; j < 4; ++j) {
            float4 f0 = *(const float4*)(ap + j * 8);
            float4 f1 = *(const float4*)(ap + j * 8 + 4);
            __align__(16) __hip_bfloat16 t8[8];
            t8[0] = __float2bfloat16(f0.x); t8[1] = __float2bfloat16(f0.y);
            t8[2] = __float2bfloat16(f0.z); t8[3] = __float2bfloat16(f0.w);
            t8[4] = __float2bfloat16(f1.x); t8[5] = __float2bfloat16(f1.y);
            t8[6] = __float2bfloat16(f1.z); t8[7] = __float2bfloat16(f1.w);
            *(uint4*)&As[sr * LDP + sk + j * 8] = *(const uint4*)t8;
        }
        const uint4* bp = (const uint4*)(Wt + (size_t)tid * KDIM + kc);
#pragma unroll
        for (int j = 0; j < 8; ++j)
            *(uint4*)&Bs[tid * LDP + j * 8] = bp[j];
        __syncthreads();

#pragma unroll
        for (int ks = 0; ks < 2; ++ks) {
            bf16x8 af[4], bfv[8];
#pragma unroll
            for (int i = 0; i < 4; ++i)
                af[i] = *(const bf16x8*)&As[(wr * 64 + i * 16 + m0) * LDP + ks * 32 + quad * 8];
#pragma unroll
            for (int j = 0; j < 8; ++j)
                bfv[j] = *(const bf16x8*)&Bs[(wc * 128 + j * 16 + m0) * LDP + ks * 32 + quad * 8];
#pragma unroll
            for (int i = 0; i < 4; ++i)
#pragma unroll
                for (int j = 0; j < 8; ++j)
                    acc[i][j] = __builtin_amdgcn_mfma_f32_16x16x32_bf16(af[i], bfv[j], acc[i][j], 0, 0, 0);
        }
        __syncthreads();
    }

    const int b = rowBase / LVTOT;
    const int pixBase = rowBase - b * LVTOT + wr * 64;
#pragma unroll
    for (int j = 0; j < 8; ++j) {
        const int gcol = wc * 128 + j * 16 + m0;
        const int h = gcol >> 5, c = gcol & 31;
        const float bv = bias[gcol];
        __hip_bfloat16* vp = v + ((size_t)(b * NHEAD + h) * LVTOT) * CH + c;
#pragma unroll
        for (int i = 0; i < 4; ++i) {
            const int pix0 = pixBase + i * 16 + quad * 4;
#pragma unroll
            for (int r = 0; r < 4; ++r)
                vp[(size_t)(pix0 + r) * CH] = __float2bfloat16(acc[i][j][r] + bv);
        }
    }
}

// ---------------------------------------------------------------------------
// Generic bf16 MFMA GEMM: A bf16 [M][256] @ Wt bf16 [N][256]^T + bias -> store
// Tile 128x128, 4 waves of 32x128 each (acc[2][8]).
// ---------------------------------------------------------------------------
struct StorePlain {
    float* o;
    int ncol;
    __device__ void operator()(int row, int col, float val) const {
        o[(size_t)row * ncol + col] = val;
    }
};

template <typename Store>
__global__ __launch_bounds__(256, 2)
void gemm_bf16_mfma(const __hip_bfloat16* __restrict__ A,
                    const __hip_bfloat16* __restrict__ Wt,
                    const float* __restrict__ bias, Store store) {
    __shared__ __align__(16) __hip_bfloat16 As[128 * LDP];
    __shared__ __align__(16) __hip_bfloat16 Bs[128 * LDP];

    const int tid  = threadIdx.x;
    const int lane = tid & 63;
    const int wave = tid >> 6;
    const int rowBase = blockIdx.x * 128;
    const int cb = blockIdx.y * 128;

    const int m0   = lane & 15;
    const int quad = lane >> 4;

    const int sr = tid >> 1;
    const int sk = (tid & 1) * 32;

    f32x4 acc[2][8] = {};

    for (int kc = 0; kc < KDIM; kc += BK) {
        const uint4* ap = (const uint4*)(A + (size_t)(rowBase + sr) * KDIM + kc + sk);
#pragma unroll
        for (int j = 0; j < 4; ++j)
            *(uint4*)&As[sr * LDP + sk + j * 8] = ap[j];
        const uint4* bp = (const uint4*)(Wt + (size_t)(cb + sr) * KDIM + kc + sk);
#pragma unroll
        for (int j = 0; j < 4; ++j)
            *(uint4*)&Bs[sr * LDP + sk + j * 8] = bp[j];
        __syncthreads();

#pragma unroll
        for (int ks = 0; ks < 2; ++ks) {
            bf16x8 af[2], bfv[8];
#pragma unroll
            for (int i = 0; i < 2; ++i)
                af[i] = *(const bf16x8*)&As[(wave * 32 + i * 16 + m0) * LDP + ks * 32 + quad * 8];
#pragma unroll
            for (int j = 0; j < 8; ++j)
                bfv[j] = *(const bf16x8*)&Bs[(j * 16 + m0) * LDP + ks * 32 + quad * 8];
#pragma unroll
            for (int i = 0; i < 2; ++i)
#pragma unroll
                for (int j = 0; j < 8; ++j)
                    acc[i][j] = __builtin_amdgcn_mfma_f32_16x16x32_bf16(af[i], bfv[j], acc[i][j], 0, 0, 0);
        }
        __syncthreads();
    }

#pragma unroll
    for (int j = 0; j < 8; ++j) {
        const int col = cb + j * 16 + m0;
        const float bv = bias[col];
#pragma unroll
        for (int i = 0; i < 2; ++i) {
            const int row0 = rowBase + wave * 32 + i * 16 + quad * 4;
#pragma unroll
            for (int r = 0; r < 4; ++r)
                store(row0 + r, col, acc[i][j][r] + bv);
        }
    }
}

// ---------------------------------------------------------------------------
// Fused softmax + deformable sampling, v2.
// Phase 1: 256 threads precompute per-tap corner offsets + attn-folded weights.
// Phase 2: lane = (corner-group g = lane>>4, channel-pair c2 = lane&15).
//          One wave-load covers 4 taps x 16 lanes x 4B (2 channels).
// ---------------------------------------------------------------------------
__global__ __launch_bounds__(256)
void sample_kernel(const float* __restrict__ off_ws,
                   const float* __restrict__ logits_ws,
                   const float* __restrict__ bbox,
                   const __hip_bfloat16* __restrict__ v,
                   __hip_bfloat16* __restrict__ acc_bf) {
    __shared__ __align__(16) float off_s[8 * 256];      // 8 KB
    __shared__ __align__(16) float attn_s[8 * 128];     // 4 KB
    __shared__ float bbox_s[64];                        // 256 B
    __shared__ __align__(16) int idx_s[1024 * 4];       // 16 KB
    __shared__ __align__(8) unsigned short w_s[1024 * 4]; // 8 KB

    const int tid = threadIdx.x;
    // XCD-locality swizzle: batch = blockIdx & 7 (one batch per XCD heuristic)
    const int b = blockIdx.x & 7;
    const int gq0 = b * QTOT + (blockIdx.x >> 3) * 8;

    // ---- stage off / logits / bbox ----
    const float4* osrc = (const float4*)(off_ws + (size_t)gq0 * 256);
    ((float4*)off_s)[tid] = osrc[tid];
    ((float4*)off_s)[tid + 256] = osrc[tid + 256];
    const float4* lsrc = (const float4*)(logits_ws + (size_t)gq0 * 128);
    ((float4*)attn_s)[tid] = lsrc[tid];
    if (tid < 64) bbox_s[tid] = bbox[(size_t)gq0 * 8 + tid];
    __syncthreads();

    // ---- softmax over 16 per (query, head) ----
    if (tid < 64) {
        int qq = tid >> 3, h = tid & 7;
        float* p = attn_s + qq * 128 + h * 16;
        float m = p[0];
#pragma unroll
        for (int i = 1; i < 16; ++i) m = fmaxf(m, p[i]);
        float e[16], s = 0.f;
#pragma unroll
        for (int i = 0; i < 16; ++i) { e[i] = __expf(p[i] - m); s += e[i]; }
        float inv = 1.f / s;
#pragma unroll
        for (int i = 0; i < 16; ++i) p[i] = e[i] * inv;
    }
    __syncthreads();

    // ---- phase 1: precompute 1024 taps (4 per thread) ----
#pragma unroll
    for (int r = 0; r < 4; ++r) {
        const int tap = tid + r * 256;
        const int qq = tap >> 7, h = (tap >> 4) & 7, l = (tap >> 2) & 3, p = tap & 3;
        const int Wd = 128 >> l;                    // H == W at every level
        const int st = (l == 0) ? 0 : (l == 1) ? 16384 : (l == 2) ? 20480 : 21504;

        const float bx = bbox_s[qq * 8 + l * 2 + 0];
        const float by = bbox_s[qq * 8 + l * 2 + 1];
        const float ox = off_s[qq * 256 + h * 32 + l * 8 + p * 2 + 0];
        const float oy = off_s[qq * 256 + h * 32 + l * 8 + p * 2 + 1];
        const float att = attn_s[qq * 128 + h * 16 + l * 4 + p];

        const float x = bx * (float)Wd + ox - 0.5f;
        const float y = by * (float)Wd + oy - 0.5f;
        const float x0f = floorf(x), y0f = floorf(y);
        const float fx = x - x0f, fy = y - y0f;
        const int x0 = (int)x0f, y0 = (int)y0f;
        const int x1 = x0 + 1, y1 = y0 + 1;
        const bool vx0 = (unsigned)x0 < (unsigned)Wd;
        const bool vx1 = (unsigned)x1 < (unsigned)Wd;
        const bool vy0 = (unsigned)y0 < (unsigned)Wd;
        const bool vy1 = (unsigned)y1 < (unsigned)Wd;
        const int cx0 = min(max(x0, 0), Wd - 1), cx1 = min(max(x1, 0), Wd - 1);
        const int cy0 = min(max(y0, 0), Wd - 1), cy1 = min(max(y1, 0), Wd - 1);

        int4 idx;
        idx.x = (st + cy0 * Wd + cx0) << 6;   // byte offset (CH*2B = 64)
        idx.y = (st + cy0 * Wd + cx1) << 6;
        idx.z = (st + cy1 * Wd + cx0) << 6;
        idx.w = (st + cy1 * Wd + cx1) << 6;
        float w0 = (vx0 && vy0) ? (1.f - fx) * (1.f - fy) * att : 0.f;
        float w1 = (vx1 && vy0) ? fx * (1.f - fy) * att : 0.f;
        float w2 = (vx0 && vy1) ? (1.f - fx) * fy * att : 0.f;
        float w3 = (vx1 && vy1) ? fx * fy * att : 0.f;

        *(int4*)&idx_s[tap * 4] = idx;
        unsigned short w4[4] = {f2bfu(w0), f2bfu(w1), f2bfu(w2), f2bfu(w3)};
        *(uint2*)&w_s[tap * 4] = *(const uint2*)w4;
    }
    __syncthreads();

    // ---- phase 2: gather. 4 waves x 16 (q,h) pairs each ----
    const int lane = tid & 63;
    const int wave = tid >> 6;
    const int g = lane >> 4;      // corner... tap-subgroup 0..3
    const int c2 = lane & 15;     // channel pair

    const char* vbase = (const char*)v + (size_t)b * NHEAD * LVTOT * (CH * 2) + c2 * 4;

    for (int i = 0; i < 16; ++i) {
        const int pair = wave * 16 + i;
        const int qq = pair >> 3, hh = pair & 7;
        const char* slab = vbase + (size_t)hh * LVTOT * (CH * 2);
        const int tbase = qq * 128 + hh * 16;

        float ax0 = 0.f, ay0 = 0.f, ax1 = 0.f, ay1 = 0.f, ax2 = 0.f, ay2 = 0.f, ax3 = 0.f, ay3 = 0.f;
#pragma unroll
        for (int ts = 0; ts < 4; ++ts) {
            const int tap = tbase + ts * 4 + g;
            const int4 idx = *(const int4*)&idx_s[tap * 4];
            const ushort4 ww = *(const ushort4*)&w_s[tap * 4];
            unsigned u0 = *(const unsigned*)(slab + idx.x);
            unsigned u1 = *(const unsigned*)(slab + idx.y);
            unsigned u2 = *(const unsigned*)(slab + idx.z);
            unsigned u3 = *(const unsigned*)(slab + idx.w);
            float w0 = bfu2f(ww.x), w1 = bfu2f(ww.y), w2 = bfu2f(ww.z), w3 = bfu2f(ww.w);
            ax0 += w0 * bf_lo(u0); ay0 += w0 * bf_hi(u0);
            ax1 += w1 * bf_lo(u1); ay1 += w1 * bf_hi(u1);
            ax2 += w2 * bf_lo(u2); ay2 += w2 * bf_hi(u2);
            ax3 += w3 * bf_lo(u3); ay3 += w3 * bf_hi(u3);
        }
        float sx = (ax0 + ax1) + (ax2 + ax3);
        float sy = (ay0 + ay1) + (ay2 + ay3);
        // reduce across the 4 lane-groups (xor 16, 32)
        sx += __shfl_xor(sx, 16); sy += __shfl_xor(sy, 16);
        sx += __shfl_xor(sx, 32); sy += __shfl_xor(sy, 32);
        if (g == 0) {
            __hip_bfloat16 h2[2] = {__float2bfloat16(sx), __float2bfloat16(sy)};
            unsigned packed; __builtin_memcpy(&packed, h2, 4);
            *(unsigned*)((char*)acc_bf + ((size_t)(gq0 + qq) * 256 + hh * 32 + c2 * 2) * 2) = packed;
        }
    }
}

// ---------------------------------------------------------------------------
extern "C" void kernel_launch(void* const* d_in, const int* in_sizes, int n_in,
                              void* d_out, int out_size, void* d_ws, size_t ws_size,
                              hipStream_t stream) {
    const float* query   = (const float*)d_in[0];
    const float* bbox    = (const float*)d_in[1];
    const float* value   = (const float*)d_in[2];
    const float* W_value = (const float*)d_in[4];
    const float* b_value = (const float*)d_in[5];
    const float* W_off   = (const float*)d_in[6];
    const float* b_off   = (const float*)d_in[7];
    const float* W_attn  = (const float*)d_in[8];
    const float* b_attn  = (const float*)d_in[9];
    const float* W_out   = (const float*)d_in[10];
    const float* b_out   = (const float*)d_in[11];
    float* out = (float*)d_out;

    // workspace layout (total exactly 131,072,000 B as in round 1/2)
    char* ws = (char*)d_ws;
    __hip_bfloat16* v_ws  = (__hip_bfloat16*)ws;                               // 89,128,960
    float* off_ws         = (float*)(ws + 89128960);                           // 16,777,216
    float* logits_ws      = (float*)(ws + 89128960 + 16777216);                //  8,388,608
    __hip_bfloat16* acc_bf = (__hip_bfloat16*)(ws + 89128960 + 16777216 + 8388608);      // 8,388,608
    __hip_bfloat16* q_bf   = (__hip_bfloat16*)(ws + 89128960 + 16777216 + 8388608 + 8388608); // 8,388,608

    // Wt tables overlay dead regions:
    //  - Wt_v / Wt_off / Wt_attn live in the acc_bf region; all consumed before
    //    sample_kernel writes acc_bf.
    //  - Wt_out lives in the q_bf region, converted AFTER the attn GEMM (last
    //    reader of q_bf) and consumed by the out GEMM.
    __hip_bfloat16* Wt_v    = acc_bf;                  // 131,072 B
    __hip_bfloat16* Wt_off  = acc_bf + 65536;          // 131,072 B
    __hip_bfloat16* Wt_attn = acc_bf + 131072;         //  65,536 B
    __hip_bfloat16* Wt_out  = q_bf;                    // 131,072 B

    const int NQ = BS * QTOT;          // 16384
    const int NVROWS = BS * LVTOT;     // 174080

    // 0a. query -> bf16
    convert_q<<<NQ * KDIM / 1024, 256, 0, stream>>>(query, q_bf);
    // 0b. weight transposes (value/off/attn)
    convert_W<<<256, 256, 0, stream>>>(W_value, Wt_v, 8);
    convert_W<<<256, 256, 0, stream>>>(W_off, Wt_off, 8);
    convert_W<<<128, 256, 0, stream>>>(W_attn, Wt_attn, 7);

    // 1. value projection (bf16 MFMA) -> v_ws (b, h, pix, c)
    gemm_value_mfma<<<NVROWS / 128, 256, 0, stream>>>(value, Wt_v, b_value, v_ws);

    // 2. offsets: q_bf @ Wt_off^T + b_off -> off_ws (fp32)
    gemm_bf16_mfma<<<dim3(NQ / 128, 2), 256, 0, stream>>>(
        q_bf, Wt_off, b_off, StorePlain{off_ws, 256});

    // 3. attention logits: q_bf @ Wt_attn^T + b_attn -> logits_ws (fp32)
    gemm_bf16_mfma<<<dim3(NQ / 128, 1), 256, 0, stream>>>(
        q_bf, Wt_attn, b_attn, StorePlain{logits_ws, 128});

    // 3b. W_out transpose into q_bf region (q_bf dead after step 3)
    convert_W<<<256, 256, 0, stream>>>(W_out, Wt_out, 8);

    // 4. softmax + deformable sampling -> acc_bf (bf16, overwrites Wt_v/off/attn)
    sample_kernel<<<NQ / 8, 256, 0, stream>>>(off_ws, logits_ws, bbox, v_ws, acc_bf);

    // 5. output projection -> d_out (fp32)
    gemm_bf16_mfma<<<dim3(NQ / 128, 2), 256, 0, stream>>>(
        acc_bf, Wt_out, b_out, StorePlain{out, 256});
}